// Round 4
// baseline (417.619 us; speedup 1.0000x reference)
//
#include <hip/hip_runtime.h>

typedef __attribute__((ext_vector_type(8))) short short8;
typedef __attribute__((ext_vector_type(4))) float floatx4;

__device__ __forceinline__ unsigned short f2b(float f) {
  unsigned int u = __float_as_uint(f);
  unsigned int r = (u + 0x7FFFu + ((u >> 16) & 1u)) >> 16;  // RNE
  return (unsigned short)r;
}
// load 8 fp32, convert to 8 bf16 packed in a uint4
__device__ __forceinline__ uint4 ld8f(const float* p) {
  float4 a = *(const float4*)p;
  float4 b = *(const float4*)(p + 4);
  uint4 r;
  r.x = (unsigned int)f2b(a.x) | ((unsigned int)f2b(a.y) << 16);
  r.y = (unsigned int)f2b(a.z) | ((unsigned int)f2b(a.w) << 16);
  r.z = (unsigned int)f2b(b.x) | ((unsigned int)f2b(b.y) << 16);
  r.w = (unsigned int)f2b(b.z) | ((unsigned int)f2b(b.w) << 16);
  return r;
}

// async global->LDS, 16B per lane (m97: the 874 TF staging path)
#define GLL(g, l) __builtin_amdgcn_global_load_lds( \
    (const __attribute__((address_space(1))) unsigned int*)(g), \
    (__attribute__((address_space(3))) unsigned int*)(l), 16, 0, 0)

// XCD-bijective blockIdx swizzle (T1, m204): contiguous chunk of the linear
// grid per XCD -> per-XCD L2 keeps a working set. Requires nwg % 8 == 0.
__device__ __forceinline__ void xcd_swz(int& bx, int& by, int& bz) {
  const int nx = gridDim.x, ny = gridDim.y;
  const int nwg = nx * ny * gridDim.z;
  const int lbid = blockIdx.x + nx * (blockIdx.y + ny * blockIdx.z);
  const int s = (lbid & 7) * (nwg >> 3) + (lbid >> 3);
  bx = s % nx; by = (s / nx) % ny; bz = s / (nx * ny);
}

// Depth-4 ring-buffered K-loop (T3+T4 properly sized + T2 both-sides swizzle).
// 64x128 tile, BK=32, 4 LDS slots (48KB), counted vmcnt (steady vmcnt(9):
// 3 tiles x 3 GLL in flight -> ~900cy lookahead covers HBM latency).
// Bank conflicts: original row-stride-64B frag reads were 8-way conflicted;
// fix = pre-swizzle GLOBAL source chunk (LDS dest stays linear, rule #21) and
// XOR the same key on the read side -> 2-way (free, m136). Key: (row>>1)&3,
// which is (lane>>3)&3 on the staging side and (l16>>1)&3 on the read side.
__device__ __forceinline__ void kloop(const unsigned short* __restrict__ A,
                                      const unsigned short* __restrict__ B,
                                      int K, unsigned short* ldsA, unsigned short* ldsB,
                                      floatx4 (&acc)[2][4])
{
  const int tid = threadIdx.x;
  const int w = tid >> 6, lane = tid & 63;
  const int quad = lane >> 4, l16 = lane & 15;
  const int wy = w >> 1, wx = w & 1;
  const int rsa = 16 * w + (lane >> 2);      // A staging row
  const int rsb = 32 * w + (lane >> 2);      // B staging rows (and +16)
  const int ks = ((lane & 3) ^ ((lane >> 3) & 3)) * 8;  // swizzled source chunk
  const int loa  = w * 512 + lane * 8;       // LDS dests (linear, wave-uniform+lane*16B)
  const int lob0 = w * 1024 + lane * 8;
  const int lob1 = lob0 + 512;
  const int sw = (l16 >> 1) & 3;             // read-side swizzle key
  const unsigned short* a0 = A + (size_t)rsa * K + ks;
  const unsigned short* b0 = B + (size_t)rsb * K + ks;
  const unsigned short* b1 = b0 + (size_t)16 * K;
  const int NT = K >> 5;

  // prologue: stage tiles 0..2 into slots 0..2 (9 GLLs/wave in flight)
#pragma unroll
  for (int t = 0; t < 3; ++t) {
    GLL(a0 + t * 32, &ldsA[t * 2048 + loa]);
    GLL(b0 + t * 32, &ldsB[t * 4096 + lob0]);
    GLL(b1 + t * 32, &ldsB[t * 4096 + lob1]);
  }

  for (int t = 0; t < NT; ++t) {
    if (t + 3 < NT) {
      const int s = (t + 3) & 3;
      const int k0 = (t + 3) * 32;
      GLL(a0 + k0, &ldsA[s * 2048 + loa]);
      GLL(b0 + k0, &ldsB[s * 4096 + lob0]);
      GLL(b1 + k0, &ldsB[s * 4096 + lob1]);
      asm volatile("s_waitcnt vmcnt(9)" ::: "memory");   // tile t landed; 9 stay in flight
    } else if (t + 3 == NT) {
      asm volatile("s_waitcnt vmcnt(6)" ::: "memory");
    } else if (t + 2 == NT) {
      asm volatile("s_waitcnt vmcnt(3)" ::: "memory");
    } else {
      asm volatile("s_waitcnt vmcnt(0)" ::: "memory");
    }
    __builtin_amdgcn_s_barrier();    // all waves: tile t present in slot t&3
    asm volatile("" ::: "memory");
    const int c = t & 3;
    short8 af[2], bf[4];
#pragma unroll
    for (int i = 0; i < 2; i++)
      af[i] = *(const short8*)&ldsA[c * 2048 + (wy * 32 + i * 16 + l16) * 32 + (quad ^ sw) * 8];
#pragma unroll
    for (int j = 0; j < 4; j++)
      bf[j] = *(const short8*)&ldsB[c * 4096 + (wx * 64 + j * 16 + l16) * 32 + (quad ^ sw) * 8];
#pragma unroll
    for (int i = 0; i < 2; i++)
#pragma unroll
      for (int j = 0; j < 4; j++)
        acc[i][j] = __builtin_amdgcn_mfma_f32_16x16x32_bf16(af[i], bf[j], acc[i][j], 0, 0, 0);
    __builtin_amdgcn_s_barrier();    // slot t&3 reads done -> overwritable next step
    asm volatile("" ::: "memory");
  }
}

// ---- fused QKV: C[16384,1536] split into q/k/v [16384,512] each, bias per segment
__global__ __launch_bounds__(256, 3) void gemm_qkv(
    const unsigned short* __restrict__ x,   // [16384,512] bf16
    const unsigned short* __restrict__ WT,  // [1536,512] bf16 (Wq^T;Wk^T;Wv^T)
    const float* __restrict__ bq, const float* __restrict__ bk, const float* __restrict__ bv,
    unsigned short* __restrict__ q, unsigned short* __restrict__ kx, unsigned short* __restrict__ v)
{
  __shared__ unsigned short ldsA[8192], ldsB[16384];
  int bx, by, bz;
  xcd_swz(bx, by, bz);
  const int m0 = by * 64, n0 = bx * 128;
  floatx4 acc[2][4];
#pragma unroll
  for (int i = 0; i < 2; i++)
#pragma unroll
    for (int j = 0; j < 4; j++) acc[i][j] = (floatx4){0.f, 0.f, 0.f, 0.f};

  kloop(x + (size_t)m0 * 512, WT + (size_t)n0 * 512, 512, ldsA, ldsB, acc);

  const int seg = n0 >> 9, nloc = n0 & 511;
  unsigned short* C = seg == 0 ? q : (seg == 1 ? kx : v);
  const float* bias = seg == 0 ? bq : (seg == 1 ? bk : bv);
  const int lane = threadIdx.x & 63, w = threadIdx.x >> 6;
  const int quad = lane >> 4, l16 = lane & 15, wy = w >> 1, wx = w & 1;
  float bvv[4];
#pragma unroll
  for (int j = 0; j < 4; j++) bvv[j] = bias[nloc + wx * 64 + j * 16 + l16];
#pragma unroll
  for (int i = 0; i < 2; i++)
#pragma unroll
    for (int r = 0; r < 4; r++) {
      int m = m0 + wy * 32 + i * 16 + quad * 4 + r;
      unsigned short* crow = C + (size_t)m * 512 + nloc + wx * 64 + l16;
#pragma unroll
      for (int j = 0; j < 4; j++) crow[j * 16] = f2b(acc[i][j][r] + bvv[j]);
    }
}

// ---- generic bf16 GEMM: C = act(A @ Bt^T + bias), C fp32 (CF32) or bf16
template<int CF32, int ACT>
__global__ __launch_bounds__(256, 3) void gemm2(
    const unsigned short* __restrict__ A, const unsigned short* __restrict__ Bt,
    const float* __restrict__ bias, void* __restrict__ Cv,
    int N, int K, long aB, long bB, long cB)
{
  __shared__ unsigned short ldsA[8192], ldsB[16384];
  int bx, by, bz;
  xcd_swz(bx, by, bz);
  const int b = bz;
  const int m0 = by * 64, n0 = bx * 128;
  floatx4 acc[2][4];
#pragma unroll
  for (int i = 0; i < 2; i++)
#pragma unroll
    for (int j = 0; j < 4; j++) acc[i][j] = (floatx4){0.f, 0.f, 0.f, 0.f};

  kloop(A + (size_t)b * aB + (size_t)m0 * K, Bt + (size_t)b * bB + (size_t)n0 * K,
        K, ldsA, ldsB, acc);

  const int lane = threadIdx.x & 63, w = threadIdx.x >> 6;
  const int quad = lane >> 4, l16 = lane & 15, wy = w >> 1, wx = w & 1;
  float bvv[4];
#pragma unroll
  for (int j = 0; j < 4; j++)
    bvv[j] = bias ? bias[n0 + wx * 64 + j * 16 + l16] : 0.f;
  float*          Cf = (float*)Cv          + (size_t)b * cB;
  unsigned short* Ch = (unsigned short*)Cv + (size_t)b * cB;
#pragma unroll
  for (int i = 0; i < 2; i++)
#pragma unroll
    for (int r = 0; r < 4; r++) {
      int m = m0 + wy * 32 + i * 16 + quad * 4 + r;
      size_t base = (size_t)m * N + n0 + wx * 64 + l16;
#pragma unroll
      for (int j = 0; j < 4; j++) {
        float vv = acc[i][j][r] + bvv[j];
        if (ACT == 1) vv = tanhf(vv);
        if (CF32) Cf[base + j * 16] = vv;
        else      Ch[base + j * 16] = f2b(vv);
      }
    }
}

// ---- score: E = dep ? exp(clamp((q.k)*dtab[dep])) : 0, fp32, coalesced epilogue
#define CST 132  // padded fp32 tile stride (floats): breaks row-bank aliasing
__global__ __launch_bounds__(256, 3) void score_kernel(
    const unsigned short* __restrict__ Q, const unsigned short* __restrict__ Km,
    const int* __restrict__ dep, const float* __restrict__ dept,
    float* __restrict__ E)
{
  __shared__ union {
    struct { unsigned short a[8192]; unsigned short b[16384]; } s;
    float c[32 * CST];
  } sm;
  __shared__ float dtab[64];
  const int tid = threadIdx.x;
  if (tid < 64) dtab[tid] = dept[tid];

  int bx, by, bz;
  xcd_swz(bx, by, bz);
  const int b = bz;
  const int m0 = by * 64, n0 = bx * 128;
  floatx4 acc[2][4];
#pragma unroll
  for (int i = 0; i < 2; i++)
#pragma unroll
    for (int j = 0; j < 4; j++) acc[i][j] = (floatx4){0.f, 0.f, 0.f, 0.f};

  kloop(Q + (size_t)b * (1024 * 512) + (size_t)m0 * 512,
        Km + (size_t)b * (1024 * 512) + (size_t)n0 * 512,
        512, sm.s.a, sm.s.b, acc);

  const int lane = tid & 63, w = tid >> 6;
  const int quad = lane >> 4, l16 = lane & 15, wy = w >> 1, wx = w & 1;
  const int* depb = dep + (size_t)b * 1024 * 1024;
  float* Eb = E + (size_t)b * 1024 * 1024;
  const int cr = tid >> 3, cb = (tid & 7) * 16;

#pragma unroll
  for (int i = 0; i < 2; i++) {
    __syncthreads();  // LDS free (kloop done / prior i's tile reads done)
#pragma unroll
    for (int j = 0; j < 4; j++)
#pragma unroll
      for (int r = 0; r < 4; r++)
        sm.c[(wy * 16 + quad * 4 + r) * CST + wx * 64 + j * 16 + l16] = acc[i][j][r];
    __syncthreads();
    // 32 rows x 128 cols; thread: row cr, 16 cols at cb -- all 16B accesses
    const int m = m0 + (cr >> 4) * 32 + i * 16 + (cr & 15);
    const int* dr = depb + (size_t)m * 1024 + n0 + cb;
    float* er = Eb + (size_t)m * 1024 + n0 + cb;
    const float* crow = &sm.c[cr * CST + cb];
#pragma unroll
    for (int c = 0; c < 4; c++) {
      int4 d = *(const int4*)(dr + c * 4);
      float4 s = *(const float4*)(crow + c * 4);
      float4 e;
      e.x = d.x ? __expf(fminf(fmaxf(s.x * dtab[d.x & 63], -60.f), 60.f)) : 0.f;
      e.y = d.y ? __expf(fminf(fmaxf(s.y * dtab[d.y & 63], -60.f), 60.f)) : 0.f;
      e.z = d.z ? __expf(fminf(fmaxf(s.z * dtab[d.z & 63], -60.f), 60.f)) : 0.f;
      e.w = d.w ? __expf(fminf(fmaxf(s.w * dtab[d.w & 63], -60.f), 60.f)) : 0.f;
      *(float4*)(er + c * 4) = e;
    }
  }
}

// ---- x = bf16(embed[inputs]) : one row per 64 lanes, 4 rows/block
__global__ void build_x(const float* __restrict__ embed, const int* __restrict__ inputs,
                        unsigned short* __restrict__ x)
{
  const int row = blockIdx.x * 4 + (threadIdx.x >> 6);
  const int lane = threadIdx.x & 63;
  const float* src = embed + (size_t)inputs[row] * 512 + lane * 8;
  *(uint4*)&x[(size_t)row * 512 + lane * 8] = ld8f(src);
}

// ---- all 5 weight transposes fp32->bf16 in one launch (z selects source)
__global__ void trans_w(const float* s0, const float* s1, const float* s2,
                        const float* s3, const float* s4, unsigned short* dst)
{
  __shared__ unsigned short tile[32][33];
  const int z = blockIdx.z;
  const float* src = z == 0 ? s0 : z == 1 ? s1 : z == 2 ? s2 : z == 3 ? s3 : s4;
  unsigned short* ob = dst + (size_t)z * 262144;
  int c0 = blockIdx.x * 32, r0 = blockIdx.y * 32;
  int tx = threadIdx.x & 31, ty = threadIdx.x >> 5;
  for (int i = ty; i < 32; i += 8)
    tile[i][tx] = f2b(src[(size_t)(r0 + i) * 512 + (c0 + tx)]);
  __syncthreads();
  for (int i = ty; i < 32; i += 8)
    ob[(size_t)(c0 + i) * 512 + (r0 + tx)] = tile[tx][i];
}

// ---- bf16 transpose (v -> vT), batched
__global__ void trans_v(const unsigned short* __restrict__ in, unsigned short* __restrict__ out)
{
  __shared__ unsigned short tile[32][33];
  const unsigned short* ib = in + (size_t)blockIdx.z * (1024 * 512);
  unsigned short* ob = out + (size_t)blockIdx.z * (512 * 1024);
  int c0 = blockIdx.x * 32, r0 = blockIdx.y * 32;
  int tx = threadIdx.x & 31, ty = threadIdx.x >> 5;
  for (int i = ty; i < 32; i += 8)
    tile[i][tx] = ib[(size_t)(r0 + i) * 512 + (c0 + tx)];
  __syncthreads();
  for (int i = ty; i < 32; i += 8)
    ob[(size_t)(c0 + i) * 1024 + (r0 + tx)] = tile[tx][i];
}

// ---- rows /= rowsum; also emit bf16 copy for the PV GEMM
__global__ void normalize_rows(float* __restrict__ wf, unsigned short* __restrict__ wb)
{
  size_t row = blockIdx.x;
  float4* p = (float4*)(wf + row * 1024);
  float4 u = p[threadIdx.x];
  float s = (u.x + u.y) + (u.z + u.w);
#pragma unroll
  for (int d = 1; d < 64; d <<= 1) s += __shfl_xor(s, d);
  __shared__ float acc4[4];
  if ((threadIdx.x & 63) == 0) acc4[threadIdx.x >> 6] = s;
  __syncthreads();
  float tot = (acc4[0] + acc4[1]) + (acc4[2] + acc4[3]);
  float inv = tot > 0.f ? 1.f / tot : 0.f;
  u.x *= inv; u.y *= inv; u.z *= inv; u.w *= inv;
  p[threadIdx.x] = u;
  uint2 pk;
  pk.x = (unsigned int)f2b(u.x) | ((unsigned int)f2b(u.y) << 16);
  pk.y = (unsigned int)f2b(u.z) | ((unsigned int)f2b(u.w) << 16);
  *(uint2*)&wb[row * 1024 + threadIdx.x * 4] = pk;
}

extern "C" void kernel_launch(void* const* d_in, const int* in_sizes, int n_in,
                              void* d_out, int out_size, void* d_ws, size_t ws_size,
                              hipStream_t stream)
{
  const int*   inputs     = (const int*)d_in[0];
  const int*   dependency = (const int*)d_in[1];
  const float* embed      = (const float*)d_in[2];
  const float* dept       = (const float*)d_in[3];
  const float* Wq = (const float*)d_in[4];   const float* bq = (const float*)d_in[5];
  const float* Wk = (const float*)d_in[6];   const float* bk = (const float*)d_in[7];
  const float* Wv = (const float*)d_in[8];   const float* bvv = (const float*)d_in[9];
  const float* W1 = (const float*)d_in[10];  const float* b1 = (const float*)d_in[11];
  const float* W2 = (const float*)d_in[12];  const float* b2 = (const float*)d_in[13];

  float* out  = (float*)d_out;                       // wm [16,1024,512] fp32 (32 MB)
  float* wout = out + (size_t)8388608;               // weights [16,1024,1024] fp32 (64 MB)

  // ws (shorts), high-water 36.2 MB:
  //  [0 .. 8388608)        q          -> wbf lo -> h
  //  [8388608 .. 16777216) kx         -> wbf hi
  //  [16777216 .. )        WTcat(3x) W1T W2T  (end 18087936)
  unsigned short* ws   = (unsigned short*)d_ws;
  unsigned short* q    = ws;
  unsigned short* kx   = ws + 8388608;
  unsigned short* WTc  = ws + 16777216;
  unsigned short* W1T  = ws + 17563648;
  unsigned short* W2T  = ws + 17825792;
  unsigned short* wbf  = ws;                          // [16384,1024] bf16 (32 MB)
  unsigned short* h    = ws;                          // [16384,512] bf16

  // output regions used as staging (dead before final writes):
  unsigned short* x    = (unsigned short*)wout;       // [16384,512] bf16; E overwrites later
  unsigned short* v    = (unsigned short*)out;        // [16384,512] bf16 in wm region lo
  unsigned short* vT   = (unsigned short*)out + 8388608;  // [16,512,1024] bf16 in wm hi
  unsigned short* wmp  = (unsigned short*)out;        // [16384,512] bf16 (over dead v)

  dim3 blk(256);

  trans_w<<<dim3(16, 16, 5), blk, 0, stream>>>(Wq, Wk, Wv, W1, W2, WTc);
  build_x<<<dim3(4096), blk, 0, stream>>>(embed, inputs, x);

  gemm_qkv<<<dim3(12, 256, 1), blk, 0, stream>>>(x, WTc, bq, bk, bvv, q, kx, v);

  score_kernel<<<dim3(8, 16, 16), blk, 0, stream>>>(q, kx, dependency, dept, wout);

  trans_v<<<dim3(16, 32, 16), blk, 0, stream>>>(v, vT);

  normalize_rows<<<dim3(16384), blk, 0, stream>>>(wout, wbf);

  // wm_pre = weights @ v   (bf16 x bf16, batched)
  gemm2<0, 0><<<dim3(4, 16, 16), blk, 0, stream>>>(wbf, vT, nullptr, wmp,
                                                   512, 1024, 1024L * 1024, 512L * 1024, 1024L * 512);
  // h = tanh(wm_pre @ W1^T + b1)
  gemm2<0, 1><<<dim3(4, 256, 1), blk, 0, stream>>>(wmp, W1T, b1, h, 512, 512, 0, 0, 0);
  // wm = h @ W2^T + b2  (fp32, overwrites wmp/vT staging -- both dead)
  gemm2<1, 0><<<dim3(4, 256, 1), blk, 0, stream>>>(h, W2T, b2, out, 512, 512, 0, 0, 0);
}

// Round 5
// 397.199 us; speedup vs baseline: 1.0514x; 1.0514x over previous
//
#include <hip/hip_runtime.h>

typedef __attribute__((ext_vector_type(8))) short short8;
typedef __attribute__((ext_vector_type(4))) float floatx4;

__device__ __forceinline__ unsigned short f2b(float f) {
  unsigned int u = __float_as_uint(f);
  unsigned int r = (u + 0x7FFFu + ((u >> 16) & 1u)) >> 16;  // RNE
  return (unsigned short)r;
}
// load 8 fp32, convert to 8 bf16 packed in a uint4
__device__ __forceinline__ uint4 ld8f(const float* p) {
  float4 a = *(const float4*)p;
  float4 b = *(const float4*)(p + 4);
  uint4 r;
  r.x = (unsigned int)f2b(a.x) | ((unsigned int)f2b(a.y) << 16);
  r.y = (unsigned int)f2b(a.z) | ((unsigned int)f2b(a.w) << 16);
  r.z = (unsigned int)f2b(b.x) | ((unsigned int)f2b(b.y) << 16);
  r.w = (unsigned int)f2b(b.z) | ((unsigned int)f2b(b.w) << 16);
  return r;
}

// XCD-bijective blockIdx swizzle (T1, m204): contiguous chunk of the linear
// grid per XCD -> per-XCD L2 keeps a working set. Requires nwg % 8 == 0.
__device__ __forceinline__ void xcd_swz(int& bx, int& by, int& bz) {
  const int nx = gridDim.x, ny = gridDim.y;
  const int nwg = nx * ny * gridDim.z;
  const int lbid = blockIdx.x + nx * (blockIdx.y + ny * blockIdx.z);
  const int s = (lbid & 7) * (nwg >> 3) + (lbid >> 3);
  bx = s % nx; by = (s / nx) % ny; bz = s / (nx * ny);
}

// Reg-staged double-buffered K-loop (T14 mechanism). 64x128 tile, BK=32.
// Staging: global_load_dwordx4 -> VGPR issued at step START; compiler's vmcnt
// wait lands just before the ds_write at step END -- wave-local, covered by
// this step's ds_read+MFMA, decoupled from barriers (the GLL family coupled
// tile arrival to the block barrier; 4 scheduling variants of it were all
// ~flat at 78-86us). One raw s_barrier per step, only lgkmcnt(0) before it
// (LDS-write visibility); NO vmem drain anywhere in the loop.
// Safety (1 barrier, 2 buffers): a wave's ds_reads of buf[p] are lgkm-drained
// before its own barrier, so when any wave passes the barrier all reads of
// buf[p] are done; in-step writes only touch buf[p^1]. sched_barrier(0) after
// the barrier blocks ds_read hoisting (rule 18).
__device__ __forceinline__ void kloop(const unsigned short* __restrict__ A,
                                      const unsigned short* __restrict__ B,
                                      int K, unsigned short* ldsA, unsigned short* ldsB,
                                      floatx4 (&acc)[2][4])
{
  const int tid = threadIdx.x;
  const int w = tid >> 6, lane = tid & 63;
  const int quad = lane >> 4, l16 = lane & 15;
  const int wy = w >> 1, wx = w & 1;
  const int rsa = 16 * w + (lane >> 2);      // A staging row (wave covers 16 rows)
  const int rsb = 32 * w + (lane >> 2);      // B staging rows (and +16 for 2nd load)
  const int ks = (lane & 3) * 8;             // staging k-offset (shorts)
  const int loa  = w * 512 + lane * 8;       // LDS dests (linear [row][chunk])
  const int lob0 = w * 1024 + lane * 8;
  const int lob1 = lob0 + 512;
  const unsigned short* ga  = A + (size_t)rsa * K + ks;
  const unsigned short* gb0 = B + (size_t)rsb * K + ks;
  const unsigned short* gb1 = gb0 + (size_t)16 * K;
  const int NT = K >> 5;

  // prologue: tile 0 -> regs -> buf0 (one exposed load latency per kernel)
  uint4 va  = *(const uint4*)ga;
  uint4 vb0 = *(const uint4*)gb0;
  uint4 vb1 = *(const uint4*)gb1;
  *(uint4*)&ldsA[loa]  = va;
  *(uint4*)&ldsB[lob0] = vb0;
  *(uint4*)&ldsB[lob1] = vb1;
  asm volatile("s_waitcnt lgkmcnt(0)" ::: "memory");
  __builtin_amdgcn_s_barrier();
  __builtin_amdgcn_sched_barrier(0);

  int p = 0;
  for (int t = 0; t < NT; ++t) {
    // issue next tile's loads NOW; latency rides under this step's compute
    if (t + 1 < NT) {
      const int k0 = (t + 1) * 32;
      va  = *(const uint4*)(ga + k0);
      vb0 = *(const uint4*)(gb0 + k0);
      vb1 = *(const uint4*)(gb1 + k0);
    }
    const int cb = p ? 2048 : 0, cbB = p ? 4096 : 0;
    short8 af[2], bf[4];
#pragma unroll
    for (int i = 0; i < 2; i++)
      af[i] = *(const short8*)&ldsA[cb + (wy * 32 + i * 16 + l16) * 32 + quad * 8];
#pragma unroll
    for (int j = 0; j < 4; j++)
      bf[j] = *(const short8*)&ldsB[cbB + (wx * 64 + j * 16 + l16) * 32 + quad * 8];
#pragma unroll
    for (int i = 0; i < 2; i++)
#pragma unroll
      for (int j = 0; j < 4; j++)
        acc[i][j] = __builtin_amdgcn_mfma_f32_16x16x32_bf16(af[i], bf[j], acc[i][j], 0, 0, 0);
    if (t + 1 < NT) {
      const int nb = p ? 0 : 2048, nbB = p ? 0 : 4096;
      *(uint4*)&ldsA[nb + loa]   = va;   // compiler emits wave-local vmcnt wait here
      *(uint4*)&ldsB[nbB + lob0] = vb0;
      *(uint4*)&ldsB[nbB + lob1] = vb1;
    }
    asm volatile("s_waitcnt lgkmcnt(0)" ::: "memory");
    __builtin_amdgcn_s_barrier();
    __builtin_amdgcn_sched_barrier(0);
    p ^= 1;
  }
}

// ---- fused QKV: C[16384,1536] split into q/k/v [16384,512] each, bias per segment
__global__ __launch_bounds__(256, 3) void gemm_qkv(
    const unsigned short* __restrict__ x,   // [16384,512] bf16
    const unsigned short* __restrict__ WT,  // [1536,512] bf16 (Wq^T;Wk^T;Wv^T)
    const float* __restrict__ bq, const float* __restrict__ bk, const float* __restrict__ bv,
    unsigned short* __restrict__ q, unsigned short* __restrict__ kx, unsigned short* __restrict__ v)
{
  __shared__ unsigned short ldsA[4096], ldsB[8192];
  int bx, by, bz;
  xcd_swz(bx, by, bz);
  const int m0 = by * 64, n0 = bx * 128;
  floatx4 acc[2][4];
#pragma unroll
  for (int i = 0; i < 2; i++)
#pragma unroll
    for (int j = 0; j < 4; j++) acc[i][j] = (floatx4){0.f, 0.f, 0.f, 0.f};

  kloop(x + (size_t)m0 * 512, WT + (size_t)n0 * 512, 512, ldsA, ldsB, acc);

  const int seg = n0 >> 9, nloc = n0 & 511;
  unsigned short* C = seg == 0 ? q : (seg == 1 ? kx : v);
  const float* bias = seg == 0 ? bq : (seg == 1 ? bk : bv);
  const int lane = threadIdx.x & 63, w = threadIdx.x >> 6;
  const int quad = lane >> 4, l16 = lane & 15, wy = w >> 1, wx = w & 1;
  float bvv[4];
#pragma unroll
  for (int j = 0; j < 4; j++) bvv[j] = bias[nloc + wx * 64 + j * 16 + l16];
#pragma unroll
  for (int i = 0; i < 2; i++)
#pragma unroll
    for (int r = 0; r < 4; r++) {
      int m = m0 + wy * 32 + i * 16 + quad * 4 + r;
      unsigned short* crow = C + (size_t)m * 512 + nloc + wx * 64 + l16;
#pragma unroll
      for (int j = 0; j < 4; j++) crow[j * 16] = f2b(acc[i][j][r] + bvv[j]);
    }
}

// ---- generic bf16 GEMM: C = act(A @ Bt^T + bias), C fp32 (CF32) or bf16
template<int CF32, int ACT>
__global__ __launch_bounds__(256, 3) void gemm2(
    const unsigned short* __restrict__ A, const unsigned short* __restrict__ Bt,
    const float* __restrict__ bias, void* __restrict__ Cv,
    int N, int K, long aB, long bB, long cB)
{
  __shared__ unsigned short ldsA[4096], ldsB[8192];
  int bx, by, bz;
  xcd_swz(bx, by, bz);
  const int b = bz;
  const int m0 = by * 64, n0 = bx * 128;
  floatx4 acc[2][4];
#pragma unroll
  for (int i = 0; i < 2; i++)
#pragma unroll
    for (int j = 0; j < 4; j++) acc[i][j] = (floatx4){0.f, 0.f, 0.f, 0.f};

  kloop(A + (size_t)b * aB + (size_t)m0 * K, Bt + (size_t)b * bB + (size_t)n0 * K,
        K, ldsA, ldsB, acc);

  const int lane = threadIdx.x & 63, w = threadIdx.x >> 6;
  const int quad = lane >> 4, l16 = lane & 15, wy = w >> 1, wx = w & 1;
  float bvv[4];
#pragma unroll
  for (int j = 0; j < 4; j++)
    bvv[j] = bias ? bias[n0 + wx * 64 + j * 16 + l16] : 0.f;
  float*          Cf = (float*)Cv          + (size_t)b * cB;
  unsigned short* Ch = (unsigned short*)Cv + (size_t)b * cB;
#pragma unroll
  for (int i = 0; i < 2; i++)
#pragma unroll
    for (int r = 0; r < 4; r++) {
      int m = m0 + wy * 32 + i * 16 + quad * 4 + r;
      size_t base = (size_t)m * N + n0 + wx * 64 + l16;
#pragma unroll
      for (int j = 0; j < 4; j++) {
        float vv = acc[i][j][r] + bvv[j];
        if (ACT == 1) vv = tanhf(vv);
        if (CF32) Cf[base + j * 16] = vv;
        else      Ch[base + j * 16] = f2b(vv);
      }
    }
}

// ---- score: E = dep ? exp(clamp((q.k)*dtab[dep])) : 0, fp32, coalesced epilogue
#define CST 132  // padded fp32 tile stride (floats): breaks row-bank aliasing
__global__ __launch_bounds__(256, 3) void score_kernel(
    const unsigned short* __restrict__ Q, const unsigned short* __restrict__ Km,
    const int* __restrict__ dep, const float* __restrict__ dept,
    float* __restrict__ E)
{
  __shared__ union {
    struct { unsigned short a[4096]; unsigned short b[8192]; } s;
    float c[32 * CST];
  } sm;
  __shared__ float dtab[64];
  const int tid = threadIdx.x;
  if (tid < 64) dtab[tid] = dept[tid];

  int bx, by, bz;
  xcd_swz(bx, by, bz);
  const int b = bz;
  const int m0 = by * 64, n0 = bx * 128;
  floatx4 acc[2][4];
#pragma unroll
  for (int i = 0; i < 2; i++)
#pragma unroll
    for (int j = 0; j < 4; j++) acc[i][j] = (floatx4){0.f, 0.f, 0.f, 0.f};

  kloop(Q + (size_t)b * (1024 * 512) + (size_t)m0 * 512,
        Km + (size_t)b * (1024 * 512) + (size_t)n0 * 512,
        512, sm.s.a, sm.s.b, acc);

  const int lane = tid & 63, w = tid >> 6;
  const int quad = lane >> 4, l16 = lane & 15, wy = w >> 1, wx = w & 1;
  const int* depb = dep + (size_t)b * 1024 * 1024;
  float* Eb = E + (size_t)b * 1024 * 1024;
  const int cr = tid >> 3, cb = (tid & 7) * 16;

#pragma unroll
  for (int i = 0; i < 2; i++) {
    __syncthreads();  // LDS free (kloop done / prior i's tile reads done)
#pragma unroll
    for (int j = 0; j < 4; j++)
#pragma unroll
      for (int r = 0; r < 4; r++)
        sm.c[(wy * 16 + quad * 4 + r) * CST + wx * 64 + j * 16 + l16] = acc[i][j][r];
    __syncthreads();
    // 32 rows x 128 cols; thread: row cr, 16 cols at cb -- all 16B accesses
    const int m = m0 + (cr >> 4) * 32 + i * 16 + (cr & 15);
    const int* dr = depb + (size_t)m * 1024 + n0 + cb;
    float* er = Eb + (size_t)m * 1024 + n0 + cb;
    const float* crow = &sm.c[cr * CST + cb];
#pragma unroll
    for (int c = 0; c < 4; c++) {
      int4 d = *(const int4*)(dr + c * 4);
      float4 s = *(const float4*)(crow + c * 4);
      float4 e;
      e.x = d.x ? __expf(fminf(fmaxf(s.x * dtab[d.x & 63], -60.f), 60.f)) : 0.f;
      e.y = d.y ? __expf(fminf(fmaxf(s.y * dtab[d.y & 63], -60.f), 60.f)) : 0.f;
      e.z = d.z ? __expf(fminf(fmaxf(s.z * dtab[d.z & 63], -60.f), 60.f)) : 0.f;
      e.w = d.w ? __expf(fminf(fmaxf(s.w * dtab[d.w & 63], -60.f), 60.f)) : 0.f;
      *(float4*)(er + c * 4) = e;
    }
  }
}

// ---- x = bf16(embed[inputs]) : one row per 64 lanes, 4 rows/block
__global__ void build_x(const float* __restrict__ embed, const int* __restrict__ inputs,
                        unsigned short* __restrict__ x)
{
  const int row = blockIdx.x * 4 + (threadIdx.x >> 6);
  const int lane = threadIdx.x & 63;
  const float* src = embed + (size_t)inputs[row] * 512 + lane * 8;
  *(uint4*)&x[(size_t)row * 512 + lane * 8] = ld8f(src);
}

// ---- all 5 weight transposes fp32->bf16 in one launch (z selects source)
__global__ void trans_w(const float* s0, const float* s1, const float* s2,
                        const float* s3, const float* s4, unsigned short* dst)
{
  __shared__ unsigned short tile[32][33];
  const int z = blockIdx.z;
  const float* src = z == 0 ? s0 : z == 1 ? s1 : z == 2 ? s2 : z == 3 ? s3 : s4;
  unsigned short* ob = dst + (size_t)z * 262144;
  int c0 = blockIdx.x * 32, r0 = blockIdx.y * 32;
  int tx = threadIdx.x & 31, ty = threadIdx.x >> 5;
  for (int i = ty; i < 32; i += 8)
    tile[i][tx] = f2b(src[(size_t)(r0 + i) * 512 + (c0 + tx)]);
  __syncthreads();
  for (int i = ty; i < 32; i += 8)
    ob[(size_t)(c0 + i) * 512 + (r0 + tx)] = tile[tx][i];
}

// ---- bf16 transpose (v -> vT), batched
__global__ void trans_v(const unsigned short* __restrict__ in, unsigned short* __restrict__ out)
{
  __shared__ unsigned short tile[32][33];
  const unsigned short* ib = in + (size_t)blockIdx.z * (1024 * 512);
  unsigned short* ob = out + (size_t)blockIdx.z * (512 * 1024);
  int c0 = blockIdx.x * 32, r0 = blockIdx.y * 32;
  int tx = threadIdx.x & 31, ty = threadIdx.x >> 5;
  for (int i = ty; i < 32; i += 8)
    tile[i][tx] = ib[(size_t)(r0 + i) * 512 + (c0 + tx)];
  __syncthreads();
  for (int i = ty; i < 32; i += 8)
    ob[(size_t)(c0 + i) * 1024 + (r0 + tx)] = tile[tx][i];
}

// ---- rows /= rowsum; also emit bf16 copy for the PV GEMM
__global__ void normalize_rows(float* __restrict__ wf, unsigned short* __restrict__ wb)
{
  size_t row = blockIdx.x;
  float4* p = (float4*)(wf + row * 1024);
  float4 u = p[threadIdx.x];
  float s = (u.x + u.y) + (u.z + u.w);
#pragma unroll
  for (int d = 1; d < 64; d <<= 1) s += __shfl_xor(s, d);
  __shared__ float acc4[4];
  if ((threadIdx.x & 63) == 0) acc4[threadIdx.x >> 6] = s;
  __syncthreads();
  float tot = (acc4[0] + acc4[1]) + (acc4[2] + acc4[3]);
  float inv = tot > 0.f ? 1.f / tot : 0.f;
  u.x *= inv; u.y *= inv; u.z *= inv; u.w *= inv;
  p[threadIdx.x] = u;
  uint2 pk;
  pk.x = (unsigned int)f2b(u.x) | ((unsigned int)f2b(u.y) << 16);
  pk.y = (unsigned int)f2b(u.z) | ((unsigned int)f2b(u.w) << 16);
  *(uint2*)&wb[row * 1024 + threadIdx.x * 4] = pk;
}

extern "C" void kernel_launch(void* const* d_in, const int* in_sizes, int n_in,
                              void* d_out, int out_size, void* d_ws, size_t ws_size,
                              hipStream_t stream)
{
  const int*   inputs     = (const int*)d_in[0];
  const int*   dependency = (const int*)d_in[1];
  const float* embed      = (const float*)d_in[2];
  const float* dept       = (const float*)d_in[3];
  const float* Wq = (const float*)d_in[4];   const float* bq = (const float*)d_in[5];
  const float* Wk = (const float*)d_in[6];   const float* bk = (const float*)d_in[7];
  const float* Wv = (const float*)d_in[8];   const float* bvv = (const float*)d_in[9];
  const float* W1 = (const float*)d_in[10];  const float* b1 = (const float*)d_in[11];
  const float* W2 = (const float*)d_in[12];  const float* b2 = (const float*)d_in[13];

  float* out  = (float*)d_out;                       // wm [16,1024,512] fp32 (32 MB)
  float* wout = out + (size_t)8388608;               // weights [16,1024,1024] fp32 (64 MB)

  // ws (shorts), high-water 36.2 MB:
  //  [0 .. 8388608)        q          -> wbf lo -> h
  //  [8388608 .. 16777216) kx         -> wbf hi
  //  [16777216 .. )        WTcat(3x) W1T W2T  (end 18087936)
  unsigned short* ws   = (unsigned short*)d_ws;
  unsigned short* q    = ws;
  unsigned short* kx   = ws + 8388608;
  unsigned short* WTc  = ws + 16777216;
  unsigned short* W1T  = ws + 17563648;
  unsigned short* W2T  = ws + 17825792;
  unsigned short* wbf  = ws;                          // [16384,1024] bf16 (32 MB)
  unsigned short* h    = ws;                          // [16384,512] bf16

  // output regions used as staging (dead before final writes):
  unsigned short* x    = (unsigned short*)wout;       // [16384,512] bf16; E overwrites later
  unsigned short* v    = (unsigned short*)out;        // [16384,512] bf16 in wm region lo
  unsigned short* vT   = (unsigned short*)out + 8388608;  // [16,512,1024] bf16 in wm hi
  unsigned short* wmp  = (unsigned short*)out;        // [16384,512] bf16 (over dead v)

  dim3 blk(256);

  trans_w<<<dim3(16, 16, 5), blk, 0, stream>>>(Wq, Wk, Wv, W1, W2, WTc);
  build_x<<<dim3(4096), blk, 0, stream>>>(embed, inputs, x);

  gemm_qkv<<<dim3(12, 256, 1), blk, 0, stream>>>(x, WTc, bq, bk, bvv, q, kx, v);

  score_kernel<<<dim3(8, 16, 16), blk, 0, stream>>>(q, kx, dependency, dept, wout);

  trans_v<<<dim3(16, 32, 16), blk, 0, stream>>>(v, vT);

  normalize_rows<<<dim3(16384), blk, 0, stream>>>(wout, wbf);

  // wm_pre = weights @ v   (bf16 x bf16, batched)
  gemm2<0, 0><<<dim3(4, 16, 16), blk, 0, stream>>>(wbf, vT, nullptr, wmp,
                                                   512, 1024, 1024L * 1024, 512L * 1024, 1024L * 512);
  // h = tanh(wm_pre @ W1^T + b1)
  gemm2<0, 1><<<dim3(4, 256, 1), blk, 0, stream>>>(wmp, W1T, b1, h, 512, 512, 0, 0, 0);
  // wm = h @ W2^T + b2  (fp32, overwrites wmp/vT staging -- both dead)
  gemm2<1, 0><<<dim3(4, 256, 1), blk, 0, stream>>>(h, W2T, b2, out, 512, 512, 0, 0, 0);
}